// Round 9
// baseline (324.234 us; speedup 1.0000x reference)
//
#include <hip/hip_runtime.h>
#include <stdint.h>

// Problem constants
#define BB 16384
#define DD 1024
#define HH 1024
#define OO 256
#define CC 8

typedef unsigned short u16;
typedef __attribute__((ext_vector_type(4))) unsigned short u16x4;
typedef __attribute__((ext_vector_type(8))) short bf16x8;
typedef __attribute__((ext_vector_type(4))) float f32x4;

__device__ __forceinline__ u16 f2bf(float f) {
    union { float f; uint32_t u; } v; v.f = f;
    const uint32_t u = v.u;
    return (u16)((u + 0x7FFFu + ((u >> 16) & 1u)) >> 16);  // RNE
}

// async global->LDS, 16B per lane (dest must be wave-uniform base + lane*16)
#define GLDS16(g, l)                                                                   \
    __builtin_amdgcn_global_load_lds((const __attribute__((address_space(1))) void*)(g), \
                                     (__attribute__((address_space(3))) void*)(l), 16, 0, 0)

// ---------------------------------------------------------------------------
// Transpose fp32 [nmat][R][Cc] -> bf16 [nmat][Cc][R]  (W -> W^T, K-contiguous)
// ---------------------------------------------------------------------------
__global__ __launch_bounds__(256)
void transpose_bf16_kernel(const float* __restrict__ src, u16* __restrict__ dst,
                           int R, int Cc)
{
    __shared__ float t[32][33];
    const int tid = threadIdx.x;
    const int mat = blockIdx.z;
    const int r0 = blockIdx.y * 32, c0 = blockIdx.x * 32;
    {
        const int rr = tid >> 3, c4 = (tid & 7) * 4;
        const float4 v = *(const float4*)(src + ((size_t)mat * R + r0 + rr) * Cc + c0 + c4);
        t[rr][c4 + 0] = v.x; t[rr][c4 + 1] = v.y; t[rr][c4 + 2] = v.z; t[rr][c4 + 3] = v.w;
    }
    __syncthreads();
    {
        const int cc = tid >> 3, k4 = (tid & 7) * 4;
        u16x4 o;
        o[0] = f2bf(t[k4 + 0][cc]);
        o[1] = f2bf(t[k4 + 1][cc]);
        o[2] = f2bf(t[k4 + 2][cc]);
        o[3] = f2bf(t[k4 + 3][cc]);
        *(u16x4*)(dst + ((size_t)mat * Cc + c0 + cc) * R + r0 + k4) = o;
    }
}

// ---------------------------------------------------------------------------
// Logits (fp32, exact routing) + x -> bf16 + per-block class histogram.
// ---------------------------------------------------------------------------
__global__ __launch_bounds__(256)
void logits_kernel(const float* __restrict__ x, const float* __restrict__ Wc,
                   const float* __restrict__ bc, float* __restrict__ logits_out,
                   u16* __restrict__ x_bf16, int* __restrict__ class_idx,
                   int* __restrict__ hist)
{
    __shared__ float WcT[CC][DD];  // 32 KB, transposed classifier
    __shared__ int clsarr[16];
    const int tid = threadIdx.x;
    #pragma unroll
    for (int j = 0; j < 8; ++j) {
        const int f = tid + 256 * j;                 // float4 index into Wc [D][C]
        const float4 v = ((const float4*)Wc)[f];
        const int d = f >> 1, c = (f & 1) * 4;       // 4 elems share d (C=8)
        WcT[c + 0][d] = v.x; WcT[c + 1][d] = v.y; WcT[c + 2][d] = v.z; WcT[c + 3][d] = v.w;
    }
    __syncthreads();

    const int lane = tid & 63, wv = tid >> 6;
    const int row0 = blockIdx.x * 16 + wv * 4;

    float acc[4][8];
    #pragma unroll
    for (int r = 0; r < 4; ++r)
        #pragma unroll
        for (int c = 0; c < 8; ++c) acc[r][c] = 0.f;

    #pragma unroll
    for (int p = 0; p < 2; ++p) {
        float4 xv[2][4];
        #pragma unroll
        for (int rr = 0; rr < 2; ++rr) {
            const float4* xr = (const float4*)(x + (size_t)(row0 + 2 * p + rr) * DD);
            #pragma unroll
            for (int j = 0; j < 4; ++j) xv[rr][j] = xr[lane + 64 * j];
        }
        #pragma unroll
        for (int rr = 0; rr < 2; ++rr) {
            u16* xb = x_bf16 + (size_t)(row0 + 2 * p + rr) * DD;
            #pragma unroll
            for (int j = 0; j < 4; ++j) {
                const float4 v = xv[rr][j];
                u16x4 o; o[0] = f2bf(v.x); o[1] = f2bf(v.y); o[2] = f2bf(v.z); o[3] = f2bf(v.w);
                *(u16x4*)(xb + 4 * (lane + 64 * j)) = o;
            }
        }
        #pragma unroll
        for (int j = 0; j < 4; ++j) {
            const int f = lane + 64 * j;
            #pragma unroll
            for (int c = 0; c < 8; ++c) {
                const float4 w = *(const float4*)&WcT[c][4 * f];
                #pragma unroll
                for (int rr = 0; rr < 2; ++rr)
                    acc[2 * p + rr][c] += xv[rr][j].x * w.x + xv[rr][j].y * w.y
                                        + xv[rr][j].z * w.z + xv[rr][j].w * w.w;
            }
        }
    }

    #pragma unroll
    for (int off = 8; off < 64; off <<= 1)
        #pragma unroll
        for (int r = 0; r < 4; ++r)
            #pragma unroll
            for (int c = 0; c < 8; ++c)
                acc[r][c] += __shfl_xor(acc[r][c], off, 64);

    const int cls = lane >> 3;
    const float bcv = bc[cls];
    float s[4];
    #pragma unroll
    for (int r = 0; r < 4; ++r) {
        float v = acc[r][0];
        #pragma unroll
        for (int c = 1; c < 8; ++c) v = (cls == c) ? acc[r][c] : v;
        s[r] = v;
    }
    #pragma unroll
    for (int off = 1; off < 8; off <<= 1)
        #pragma unroll
        for (int r = 0; r < 4; ++r) s[r] += __shfl_xor(s[r], off, 64);
    #pragma unroll
    for (int r = 0; r < 4; ++r) s[r] += bcv;

    #pragma unroll
    for (int r = 0; r < 4; ++r)
        if ((lane & 7) == 0) logits_out[(size_t)(row0 + r) * CC + cls] = s[r];

    int idx[4] = {cls, cls, cls, cls};
    #pragma unroll
    for (int off = 8; off < 64; off <<= 1) {
        #pragma unroll
        for (int r = 0; r < 4; ++r) {
            const float ov = __shfl_xor(s[r], off, 64);
            const int oi = __shfl_xor(idx[r], off, 64);
            const bool take = (ov > s[r]) || (ov == s[r] && oi < idx[r]);
            s[r] = take ? ov : s[r];
            idx[r] = take ? oi : idx[r];
        }
    }
    if (lane == 0) {
        #pragma unroll
        for (int r = 0; r < 4; ++r) {
            class_idx[row0 + r] = idx[r];
            clsarr[wv * 4 + r] = idx[r];
        }
    }
    __syncthreads();
    if (tid < 64) {
        const int myc = (tid < 16) ? clsarr[tid] : -1;
        int h = 0;
        #pragma unroll
        for (int cc = 0; cc < 8; ++cc) {
            const int p = __popcll(__ballot(myc == cc));
            h = (tid == cc) ? p : h;
        }
        if (tid < 8) hist[blockIdx.x * 8 + tid] = h;
    }
}

// ---------------------------------------------------------------------------
// Single-block scan: per-class totals -> padded offsets (256-granular) +
// per-block scatter bases.
// ---------------------------------------------------------------------------
__global__ __launch_bounds__(256)
void scan_kernel(const int* __restrict__ hist, int* __restrict__ offsets,
                 int* __restrict__ bb)
{
    const int t = threadIdx.x, c = t >> 5, g = t & 31;
    int sum = 0;
    #pragma unroll 4
    for (int i = 0; i < 32; ++i) sum += hist[(g * 32 + i) * 8 + c];
    int inc = sum;
    #pragma unroll
    for (int d = 1; d < 32; d <<= 1) {
        const int v = __shfl_up(inc, d, 32);
        if (g >= d) inc += v;
    }
    __shared__ int tot[8], offL[9];
    if (g == 31) tot[c] = inc;
    __syncthreads();
    if (t == 0) {
        int o = 0; offL[0] = 0; offsets[0] = 0;
        #pragma unroll
        for (int c8 = 0; c8 < 8; ++c8) {
            o += (tot[c8] + 255) & ~255;          // pad to 256 (BM of layer GEMMs)
            offL[c8 + 1] = o; offsets[c8 + 1] = o;
        }
    }
    __syncthreads();
    int base = offL[c] + (inc - sum);
    #pragma unroll 4
    for (int i = 0; i < 32; ++i) {
        const int b = g * 32 + i;
        bb[b * 8 + c] = base;
        base += hist[b * 8 + c];
    }
}

// ---------------------------------------------------------------------------
// Scatter row ids into per-class segments — atomic-free via ballot ranking.
// ---------------------------------------------------------------------------
__global__ __launch_bounds__(256)
void scatter_kernel(const int* __restrict__ class_idx, const int* __restrict__ bb,
                    int* __restrict__ rowidx)
{
    const int r = blockIdx.x * 256 + threadIdx.x;
    const int c = class_idx[r];
    const int lane = threadIdx.x & 63;
    const int gl = lane & ~15;
    const unsigned long long before = (1ull << lane) - (1ull << gl);
    int rank = 0;
    #pragma unroll
    for (int cc = 0; cc < 8; ++cc) {
        const unsigned long long m = __ballot(c == cc);
        const int p = __popcll(m & before);
        rank = (c == cc) ? p : rank;
    }
    rowidx[bb[(r >> 4) * 8 + c] + rank] = r;
}

// ---------------------------------------------------------------------------
// R9 main GEMM (layers 1-3): faithful m201 8-phase port, adapted shape.
// BM=BN=256, BK=64, 512 thr / 8 waves (2M x 4N), wave = 128x64 out.
// LDS 128 KB: A,B each [2 buf][2 kh-plane][256 rows/cols][32 u16].
// Per K-tile: 4 phases {ds_read (10 or 2 b128); stage 1 half-tile (2 glds);
// [vmcnt(4) in Ph2,Ph4]; s_barrier; lgkmcnt(0)+sched_barrier; setprio(1);
// 16 MFMA; setprio(0); s_barrier}. Tile t stages t+1's 4 halves in its 4
// phase-slots (A-kh0, B-kh0, A-kh1, B-kh1). vmcnt(4)@Ph2 certifies prev
// tile's Ph3/Ph4 stages (= this tile's kh1 planes); vmcnt(4)@Ph4 certifies
// this tile's Ph1/Ph2 stages (= next tile's kh0 planes). Counted, never 0.
// W-A-R: stage targets buf^1 regions last read >=2 barriers earlier.
// Swizzle: phys_chunk = logc ^ ((row>>1)&3) both sides (R6-validated, =0
// conflicts for 64B rows). T1 XCD swizzle, n0-inner. T5 setprio.
// ---------------------------------------------------------------------------
#define MF(a, b, c) __builtin_amdgcn_mfma_f32_16x16x32_bf16((a), (b), (c), 0, 0, 0)
#define BAR __builtin_amdgcn_s_barrier()
#define SB0 __builtin_amdgcn_sched_barrier(0)
#define LGKM0 { asm volatile("s_waitcnt lgkmcnt(0)" ::: "memory"); SB0; }
#define VMC(N) asm volatile("s_waitcnt vmcnt(" #N ")" ::: "memory")

template<bool GATHER_A>
__global__ __launch_bounds__(512, 2)
void gemm2s_kernel(const u16* __restrict__ Abase, const u16* __restrict__ Wbase,
                   size_t wclass_stride, const float* __restrict__ bias_base,
                   int bias_stride, const int* __restrict__ offsets,
                   const int* __restrict__ rowidx, u16* __restrict__ Hout)
{
    __shared__ u16 sA[2 * 16384];   // 64 KB: [buf][kh][256][32]
    __shared__ u16 sB[2 * 16384];   // 64 KB
    const int tid = threadIdx.x;

    // XCD-chunked bijective swizzle (grid % 8 == 0), n0-inner
    const int bid = blockIdx.x;
    const int wg = (bid & 7) * ((int)gridDim.x >> 3) + (bid >> 3);
    const int m0 = (wg >> 2) * 256;
    const int n0 = (wg & 3) * 256;
    if (m0 >= offsets[CC]) return;
    int c = 0;
    while (m0 >= offsets[c + 1]) ++c;          // offsets are 256-multiples

    // ---- staging precompute (2 glds per half-tile per thread) ----
    const u16* gA[2]; const u16* gB[2];
    int dL[2];                                  // LDS u16 offset within a plane
    const u16* const Wcl = Wbase + (size_t)c * wclass_stride;
    #pragma unroll
    for (int j = 0; j < 2; ++j) {
        const int n = tid + 512 * j;            // chunk id in plane (1024 = 256x4)
        const int row = n >> 2;
        const int logc = (n & 3) ^ ((row >> 1) & 3);   // inverse swizzle on src
        int grow = m0 + row;
        if (GATHER_A) { const int g = rowidx[grow]; grow = (g < 0) ? 0 : g; }
        gA[j] = Abase + (size_t)grow * 1024 + logc * 8;
        gB[j] = Wcl + (size_t)(n0 + row) * 1024 + logc * 8;
        dL[j] = n * 8;                          // linear LDS dest (lane-affine)
    }

#define STA(XB, KH, KT)                                                        \
    { GLDS16(gA[0] + (KT) * 64 + (KH) * 32, sA + (XB) * 16384 + (KH) * 8192 + dL[0]); \
      GLDS16(gA[1] + (KT) * 64 + (KH) * 32, sA + (XB) * 16384 + (KH) * 8192 + dL[1]); }
#define STB(XB, KH, KT)                                                        \
    { GLDS16(gB[0] + (KT) * 64 + (KH) * 32, sB + (XB) * 16384 + (KH) * 8192 + dL[0]); \
      GLDS16(gB[1] + (KT) * 64 + (KH) * 32, sB + (XB) * 16384 + (KH) * 8192 + dL[1]); }

    // ---- fragment read bases (swizzled; sw constant across mi/ni) ----
    const int wv = tid >> 6, ln = tid & 63;
    const int wm = wv >> 2, wn = wv & 3;        // 2M x 4N wave grid
    const int lr = ln & 15, lg = ln >> 4;
    const int sw = lg ^ ((lr >> 1) & 3);
    const int aoff = (wm * 128 + lr) * 32 + sw * 8;   // + mi*512, + kh*8192
    const int boff = (wn * 64 + lr) * 32 + sw * 8;    // + ni*512, + kh*8192

    f32x4 acc[8][4];
    #pragma unroll
    for (int i = 0; i < 8; ++i)
        #pragma unroll
        for (int j = 0; j < 4; ++j)
            acc[i][j] = (f32x4){0.f, 0.f, 0.f, 0.f};

    // One K-tile = 4 phases. X = read buf; stages go to X^1 for tile KT.
#define TILE2(X, KT, DOST, PH2VM)                                              \
    {                                                                          \
        const u16* const pA0 = sA + (X) * 16384 + aoff;                        \
        const u16* const pB0 = sB + (X) * 16384 + boff;                        \
        bf16x8 av0, av1, av2, av3, av4, av5, av6, av7, b0, b1;                 \
        /* Ph1: A kh0 (8) + B kh0 ni{0,1} (2) */                               \
        av0 = *(const bf16x8*)(pA0);        av1 = *(const bf16x8*)(pA0 + 512); \
        av2 = *(const bf16x8*)(pA0 + 1024); av3 = *(const bf16x8*)(pA0 + 1536);\
        av4 = *(const bf16x8*)(pA0 + 2048); av5 = *(const bf16x8*)(pA0 + 2560);\
        av6 = *(const bf16x8*)(pA0 + 3072); av7 = *(const bf16x8*)(pA0 + 3584);\
        b0 = *(const bf16x8*)(pB0); b1 = *(const bf16x8*)(pB0 + 512);          \
        if (DOST) STA((X) ^ 1, 0, KT);                                         \
        BAR; LGKM0;                                                            \
        __builtin_amdgcn_s_setprio(1);                                         \
        acc[0][0] = MF(av0, b0, acc[0][0]); acc[0][1] = MF(av0, b1, acc[0][1]);\
        acc[1][0] = MF(av1, b0, acc[1][0]); acc[1][1] = MF(av1, b1, acc[1][1]);\
        acc[2][0] = MF(av2, b0, acc[2][0]); acc[2][1] = MF(av2, b1, acc[2][1]);\
        acc[3][0] = MF(av3, b0, acc[3][0]); acc[3][1] = MF(av3, b1, acc[3][1]);\
        acc[4][0] = MF(av4, b0, acc[4][0]); acc[4][1] = MF(av4, b1, acc[4][1]);\
        acc[5][0] = MF(av5, b0, acc[5][0]); acc[5][1] = MF(av5, b1, acc[5][1]);\
        acc[6][0] = MF(av6, b0, acc[6][0]); acc[6][1] = MF(av6, b1, acc[6][1]);\
        acc[7][0] = MF(av7, b0, acc[7][0]); acc[7][1] = MF(av7, b1, acc[7][1]);\
        __builtin_amdgcn_s_setprio(0);                                         \
        BAR;                                                                   \
        /* Ph2: B kh0 ni{2,3} */                                               \
        b0 = *(const bf16x8*)(pB0 + 1024); b1 = *(const bf16x8*)(pB0 + 1536);  \
        if (DOST) STB((X) ^ 1, 0, KT);                                         \
        VMC(PH2VM);                                                            \
        BAR; LGKM0;                                                            \
        __builtin_amdgcn_s_setprio(1);                                         \
        acc[0][2] = MF(av0, b0, acc[0][2]); acc[0][3] = MF(av0, b1, acc[0][3]);\
        acc[1][2] = MF(av1, b0, acc[1][2]); acc[1][3] = MF(av1, b1, acc[1][3]);\
        acc[2][2] = MF(av2, b0, acc[2][2]); acc[2][3] = MF(av2, b1, acc[2][3]);\
        acc[3][2] = MF(av3, b0, acc[3][2]); acc[3][3] = MF(av3, b1, acc[3][3]);\
        acc[4][2] = MF(av4, b0, acc[4][2]); acc[4][3] = MF(av4, b1, acc[4][3]);\
        acc[5][2] = MF(av5, b0, acc[5][2]); acc[5][3] = MF(av5, b1, acc[5][3]);\
        acc[6][2] = MF(av6, b0, acc[6][2]); acc[6][3] = MF(av6, b1, acc[6][3]);\
        acc[7][2] = MF(av7, b0, acc[7][2]); acc[7][3] = MF(av7, b1, acc[7][3]);\
        __builtin_amdgcn_s_setprio(0);                                         \
        BAR;                                                                   \
        /* Ph3: A kh1 (8) + B kh1 ni{0,1} (2) */                               \
        av0 = *(const bf16x8*)(pA0 + 8192);        av1 = *(const bf16x8*)(pA0 + 8704); \
        av2 = *(const bf16x8*)(pA0 + 9216);  av3 = *(const bf16x8*)(pA0 + 9728);       \
        av4 = *(const bf16x8*)(pA0 + 10240); av5 = *(const bf16x8*)(pA0 + 10752);      \
        av6 = *(const bf16x8*)(pA0 + 11264); av7 = *(const bf16x8*)(pA0 + 11776);      \
        b0 = *(const bf16x8*)(pB0 + 8192); b1 = *(const bf16x8*)(pB0 + 8704);  \
        if (DOST) STA((X) ^ 1, 1, KT);                                         \
        BAR; LGKM0;                                                            \
        __builtin_amdgcn_s_setprio(1);                                         \
        acc[0][0] = MF(av0, b0, acc[0][0]); acc[0][1] = MF(av0, b1, acc[0][1]);\
        acc[1][0] = MF(av1, b0, acc[1][0]); acc[1][1] = MF(av1, b1, acc[1][1]);\
        acc[2][0] = MF(av2, b0, acc[2][0]); acc[2][1] = MF(av2, b1, acc[2][1]);\
        acc[3][0] = MF(av3, b0, acc[3][0]); acc[3][1] = MF(av3, b1, acc[3][1]);\
        acc[4][0] = MF(av4, b0, acc[4][0]); acc[4][1] = MF(av4, b1, acc[4][1]);\
        acc[5][0] = MF(av5, b0, acc[5][0]); acc[5][1] = MF(av5, b1, acc[5][1]);\
        acc[6][0] = MF(av6, b0, acc[6][0]); acc[6][1] = MF(av6, b1, acc[6][1]);\
        acc[7][0] = MF(av7, b0, acc[7][0]); acc[7][1] = MF(av7, b1, acc[7][1]);\
        __builtin_amdgcn_s_setprio(0);                                         \
        BAR;                                                                   \
        /* Ph4: B kh1 ni{2,3} */                                               \
        b0 = *(const bf16x8*)(pB0 + 9216); b1 = *(const bf16x8*)(pB0 + 9728);  \
        if (DOST) { STB((X) ^ 1, 1, KT); VMC(4); }                             \
        BAR; LGKM0;                                                            \
        __builtin_amdgcn_s_setprio(1);                                         \
        acc[0][2] = MF(av0, b0, acc[0][2]); acc[0][3] = MF(av0, b1, acc[0][3]);\
        acc[1][2] = MF(av1, b0, acc[1][2]); acc[1][3] = MF(av1, b1, acc[1][3]);\
        acc[2][2] = MF(av2, b0, acc[2][2]); acc[2][3] = MF(av2, b1, acc[2][3]);\
        acc[3][2] = MF(av3, b0, acc[3][2]); acc[3][3] = MF(av3, b1, acc[3][3]);\
        acc[4][2] = MF(av4, b0, acc[4][2]); acc[4][3] = MF(av4, b1, acc[4][3]);\
        acc[5][2] = MF(av5, b0, acc[5][2]); acc[5][3] = MF(av5, b1, acc[5][3]);\
        acc[6][2] = MF(av6, b0, acc[6][2]); acc[6][3] = MF(av6, b1, acc[6][3]);\
        acc[7][2] = MF(av7, b0, acc[7][2]); acc[7][3] = MF(av7, b1, acc[7][3]);\
        __builtin_amdgcn_s_setprio(0);                                         \
        BAR;                                                                   \
    }

    // prologue: stage all 4 halves of tile 0 into buf 0, drain once
    STA(0, 0, 0); STB(0, 0, 0); STA(0, 1, 0); STB(0, 1, 0);
    VMC(0);
    BAR; SB0;

    // 16 K-tiles; tile t reads buf t&1, stages t+1 into buf (t&1)^1
    for (int t = 0; t < 14; t += 2) {
        TILE2(0, t + 1, true, 4);
        TILE2(1, t + 2, true, 4);
    }
    TILE2(0, 15, true, 4);    // t=14
    TILE2(1, 0, false, 0);    // t=15: no stages; Ph2 drains last 4

#undef TILE2
#undef STB
#undef STA

    // epilogue: C/D layout col=lane&15, row=(lane>>4)*4+reg; bias + ReLU
    const float* bp = bias_base + (size_t)c * bias_stride + n0 + wn * 64 + lr;
    #pragma unroll
    for (int ni = 0; ni < 4; ++ni) {
        const float bv = bp[ni * 16];
        const int col = n0 + wn * 64 + ni * 16 + lr;
        #pragma unroll
        for (int mi = 0; mi < 8; ++mi) {
            const int rb = m0 + wm * 128 + mi * 16 + lg * 4;
            #pragma unroll
            for (int q = 0; q < 4; ++q) {
                float v = acc[mi][ni][q] + bv;
                v = v > 0.f ? v : 0.f;
                Hout[(size_t)(rb + q) * HH + col] = f2bf(v);
            }
        }
    }
}

// ---------------------------------------------------------------------------
// L4 GEMM (N=256, final scatter): proven R5 structure, BM=BN=128, BK=32.
// ---------------------------------------------------------------------------
#define STAGE(b, kt)                            \
    {                                           \
        const int kb_ = (kt) * 32;              \
        GLDS16(gA0 + kb_, lA0 + (b) * 4096);    \
        GLDS16(gA1 + kb_, lA1 + (b) * 4096);    \
        GLDS16(gB0 + kb_, lB0 + (b) * 4096);    \
        GLDS16(gB1 + kb_, lB1 + (b) * 4096);    \
    }

#define COMPUTE(b)                                                        \
    {                                                                     \
        bf16x8 af[4], bfr[4];                                             \
        _Pragma("unroll")                                                 \
        for (int i = 0; i < 4; ++i) {                                     \
            af[i]  = *(const bf16x8*)(fA + (b) * 4096 + i * 16 * 32);     \
            bfr[i] = *(const bf16x8*)(fB + (b) * 4096 + i * 16 * 32);     \
        }                                                                 \
        __builtin_amdgcn_s_setprio(1);                                    \
        _Pragma("unroll")                                                 \
        for (int mi = 0; mi < 4; ++mi)                                    \
            _Pragma("unroll")                                             \
            for (int ni = 0; ni < 4; ++ni)                                \
                acc[mi][ni] = __builtin_amdgcn_mfma_f32_16x16x32_bf16(    \
                    af[mi], bfr[ni], acc[mi][ni], 0, 0, 0);               \
        __builtin_amdgcn_s_setprio(0);                                    \
    }

#define WAITV(N)                                                          \
    asm volatile("s_waitcnt vmcnt(" #N ")" ::: "memory");                 \
    __builtin_amdgcn_s_barrier();                                         \
    __builtin_amdgcn_sched_barrier(0);

__global__ __launch_bounds__(256, 3)
void gemm_final_kernel(const u16* __restrict__ Abase, const u16* __restrict__ Wbase,
                       size_t wclass_stride, const float* __restrict__ bias_base,
                       int bias_stride, const int* __restrict__ offsets,
                       const int* __restrict__ rowidx, float* __restrict__ Fout)
{
    __shared__ u16 sA[3 * 128 * 32];
    __shared__ u16 sB[3 * 128 * 32];
    const int tid = threadIdx.x;

    const int bid = blockIdx.x;
    const int wg = (bid & 7) * ((int)gridDim.x >> 3) + (bid >> 3);
    const int m0 = (wg >> 1) * 128;
    const int n0 = (wg & 1) * 128;
    if (m0 >= offsets[CC]) return;
    int c = 0;
    while (m0 >= offsets[c + 1]) ++c;

    const int srow = tid >> 2;
    const int kc8 = (tid & 3) * 8;
    const int sa0 = m0 + srow, sa1 = m0 + srow + 64;
    const u16* gA0 = Abase + (size_t)sa0 * 1024 + kc8;
    const u16* gA1 = Abase + (size_t)sa1 * 1024 + kc8;
    const u16* Wcl = Wbase + (size_t)c * wclass_stride;
    const u16* gB0 = Wcl + (size_t)(n0 + srow) * 1024 + kc8;
    const u16* gB1 = Wcl + (size_t)(n0 + srow + 64) * 1024 + kc8;
    u16* lA0 = sA + tid * 8;
    u16* lA1 = sA + 2048 + tid * 8;
    u16* lB0 = sB + tid * 8;
    u16* lB1 = sB + 2048 + tid * 8;

    const int lane = tid & 63, wv = tid >> 6;
    const int wm = (wv & 1) * 64, wn = (wv >> 1) * 64;
    const int lr = lane & 15, lg = lane >> 4;
    const u16* fA = sA + (wm + lr) * 32 + lg * 8;
    const u16* fB = sB + (wn + lr) * 32 + lg * 8;

    f32x4 acc[4][4];
    #pragma unroll
    for (int i = 0; i < 4; ++i)
        #pragma unroll
        for (int j = 0; j < 4; ++j)
            acc[i][j] = (f32x4){0.f, 0.f, 0.f, 0.f};

    STAGE(0, 0);
    STAGE(1, 1);
    for (int kt = 0; kt < 30; kt += 3) {
        WAITV(4);
        STAGE(2, kt + 2);
        COMPUTE(0);
        WAITV(4);
        STAGE(0, kt + 3);
        COMPUTE(1);
        WAITV(4);
        STAGE(1, kt + 4);
        COMPUTE(2);
    }
    WAITV(4);
    COMPUTE(0);
    WAITV(0);
    COMPUTE(1);

    const float* bp = bias_base + (size_t)c * bias_stride + n0 + wn + lr;
    #pragma unroll
    for (int ni = 0; ni < 4; ++ni) {
        const float bv = bp[ni * 16];
        const int col = n0 + wn + ni * 16 + lr;
        #pragma unroll
        for (int mi = 0; mi < 4; ++mi) {
            const int rb = m0 + wm + mi * 16 + lg * 4;
            #pragma unroll
            for (int q = 0; q < 4; ++q) {
                const float v = acc[mi][ni][q] + bv;
                const int orow = rowidx[rb + q];
                if (orow >= 0) Fout[(size_t)orow * OO + col] = v;
            }
        }
    }
}

// ---------------------------------------------------------------------------
extern "C" void kernel_launch(void* const* d_in, const int* in_sizes, int n_in,
                              void* d_out, int out_size, void* d_ws, size_t ws_size,
                              hipStream_t stream)
{
    const float* x  = (const float*)d_in[0];
    const float* Wc = (const float*)d_in[1];
    const float* bc = (const float*)d_in[2];
    const float* W1 = (const float*)d_in[3];
    const float* b1 = (const float*)d_in[4];
    const float* W2 = (const float*)d_in[5];
    const float* b2 = (const float*)d_in[6];
    const float* Wo = (const float*)d_in[7];
    const float* bo = (const float*)d_in[8];
    float* out    = (float*)d_out;                 // [B][O]
    float* logits = out + (size_t)BB * OO;         // [B][C]

    char* ws = (char*)d_ws;
    constexpr size_t PADMAX = BB + CC * 256;       // 18432 padded rows max
    constexpr int NLB = BB / 16;                   // 1024 logits blocks
    int* offsets   = (int*)(ws + 0);               // [9]
    int* hist      = (int*)(ws + 64);              // [NLB][8]
    int* bb        = (int*)(ws + 64 + NLB * 32);   // [NLB][8]
    int* class_idx = (int*)(ws + 64 + 2 * NLB * 32);
    int* rowidx    = (int*)((char*)class_idx + (size_t)BB * 4);
    u16* x_bf16    = (u16*)((char*)rowidx + PADMAX * 4);
    u16* hA  = x_bf16 + (size_t)BB * DD;
    u16* hB  = hA + PADMAX * HH;
    u16* W1T = hB + PADMAX * HH;                    // [C][H][D]
    u16* W2T = W1T + (size_t)CC * DD * HH;          // [C][2][H][H]
    u16* WoT = W2T + (size_t)CC * 2 * HH * HH;      // [C][O][H]

    hipMemsetAsync(rowidx, 0xFF, PADMAX * 4, stream);  // pad slots = -1

    transpose_bf16_kernel<<<dim3(32, 32, 8),  256, 0, stream>>>(W1, W1T, DD, HH);
    transpose_bf16_kernel<<<dim3(32, 32, 16), 256, 0, stream>>>(W2, W2T, HH, HH);
    transpose_bf16_kernel<<<dim3(8, 32, 8),   256, 0, stream>>>(Wo, WoT, HH, OO);

    logits_kernel<<<NLB, 256, 0, stream>>>(x, Wc, bc, logits, x_bf16, class_idx, hist);
    scan_kernel<<<1, 256, 0, stream>>>(hist, offsets, bb);
    scatter_kernel<<<BB / 256, 256, 0, stream>>>(class_idx, bb, rowidx);

    constexpr int MT2 = (int)(PADMAX / 256);  // 72 M-tiles (256-row)
    constexpr int MT4 = (int)(PADMAX / 128);  // 144 M-tiles (128-row, L4)
    gemm2s_kernel<true ><<<dim3(MT2 * 4), 512, 0, stream>>>(
        x_bf16, W1T, (size_t)DD * HH, b1, HH, offsets, rowidx, hA);
    gemm2s_kernel<false><<<dim3(MT2 * 4), 512, 0, stream>>>(
        hA, W2T, (size_t)2 * HH * HH, b2, 2 * HH, offsets, rowidx, hB);
    gemm2s_kernel<false><<<dim3(MT2 * 4), 512, 0, stream>>>(
        hB, W2T + (size_t)HH * HH, (size_t)2 * HH * HH, b2 + HH, 2 * HH, offsets, rowidx, hA);
    gemm_final_kernel<<<dim3(MT4 * 2), 256, 0, stream>>>(
        hA, WoT, (size_t)OO * HH, bo, OO, offsets, rowidx, out);
}

// Round 10
// 321.571 us; speedup vs baseline: 1.0083x; 1.0083x over previous
//
#include <hip/hip_runtime.h>
#include <stdint.h>

// Problem constants
#define BB 16384
#define DD 1024
#define HH 1024
#define OO 256
#define CC 8

typedef unsigned short u16;
typedef __attribute__((ext_vector_type(4))) unsigned short u16x4;
typedef __attribute__((ext_vector_type(8))) short bf16x8;
typedef __attribute__((ext_vector_type(4))) float f32x4;

__device__ __forceinline__ u16 f2bf(float f) {
    union { float f; uint32_t u; } v; v.f = f;
    const uint32_t u = v.u;
    return (u16)((u + 0x7FFFu + ((u >> 16) & 1u)) >> 16);  // RNE
}

// async global->LDS, 16B per lane (dest must be wave-uniform base + lane*16)
#define GLDS16(g, l)                                                                   \
    __builtin_amdgcn_global_load_lds((const __attribute__((address_space(1))) void*)(g), \
                                     (__attribute__((address_space(3))) void*)(l), 16, 0, 0)

// ---------------------------------------------------------------------------
// Transpose fp32 [nmat][R][Cc] -> bf16 [nmat][Cc][R]  (W -> W^T, K-contiguous)
// ---------------------------------------------------------------------------
__global__ __launch_bounds__(256)
void transpose_bf16_kernel(const float* __restrict__ src, u16* __restrict__ dst,
                           int R, int Cc)
{
    __shared__ float t[32][33];
    const int tid = threadIdx.x;
    const int mat = blockIdx.z;
    const int r0 = blockIdx.y * 32, c0 = blockIdx.x * 32;
    {
        const int rr = tid >> 3, c4 = (tid & 7) * 4;
        const float4 v = *(const float4*)(src + ((size_t)mat * R + r0 + rr) * Cc + c0 + c4);
        t[rr][c4 + 0] = v.x; t[rr][c4 + 1] = v.y; t[rr][c4 + 2] = v.z; t[rr][c4 + 3] = v.w;
    }
    __syncthreads();
    {
        const int cc = tid >> 3, k4 = (tid & 7) * 4;
        u16x4 o;
        o[0] = f2bf(t[k4 + 0][cc]);
        o[1] = f2bf(t[k4 + 1][cc]);
        o[2] = f2bf(t[k4 + 2][cc]);
        o[3] = f2bf(t[k4 + 3][cc]);
        *(u16x4*)(dst + ((size_t)mat * Cc + c0 + cc) * R + r0 + k4) = o;
    }
}

// ---------------------------------------------------------------------------
// Logits (fp32, exact routing) + x -> bf16 + per-block class histogram.
// ---------------------------------------------------------------------------
__global__ __launch_bounds__(256)
void logits_kernel(const float* __restrict__ x, const float* __restrict__ Wc,
                   const float* __restrict__ bc, float* __restrict__ logits_out,
                   u16* __restrict__ x_bf16, int* __restrict__ class_idx,
                   int* __restrict__ hist)
{
    __shared__ float WcT[CC][DD];  // 32 KB, transposed classifier
    __shared__ int clsarr[16];
    const int tid = threadIdx.x;
    #pragma unroll
    for (int j = 0; j < 8; ++j) {
        const int f = tid + 256 * j;                 // float4 index into Wc [D][C]
        const float4 v = ((const float4*)Wc)[f];
        const int d = f >> 1, c = (f & 1) * 4;       // 4 elems share d (C=8)
        WcT[c + 0][d] = v.x; WcT[c + 1][d] = v.y; WcT[c + 2][d] = v.z; WcT[c + 3][d] = v.w;
    }
    __syncthreads();

    const int lane = tid & 63, wv = tid >> 6;
    const int row0 = blockIdx.x * 16 + wv * 4;

    float acc[4][8];
    #pragma unroll
    for (int r = 0; r < 4; ++r)
        #pragma unroll
        for (int c = 0; c < 8; ++c) acc[r][c] = 0.f;

    #pragma unroll
    for (int p = 0; p < 2; ++p) {
        float4 xv[2][4];
        #pragma unroll
        for (int rr = 0; rr < 2; ++rr) {
            const float4* xr = (const float4*)(x + (size_t)(row0 + 2 * p + rr) * DD);
            #pragma unroll
            for (int j = 0; j < 4; ++j) xv[rr][j] = xr[lane + 64 * j];
        }
        #pragma unroll
        for (int rr = 0; rr < 2; ++rr) {
            u16* xb = x_bf16 + (size_t)(row0 + 2 * p + rr) * DD;
            #pragma unroll
            for (int j = 0; j < 4; ++j) {
                const float4 v = xv[rr][j];
                u16x4 o; o[0] = f2bf(v.x); o[1] = f2bf(v.y); o[2] = f2bf(v.z); o[3] = f2bf(v.w);
                *(u16x4*)(xb + 4 * (lane + 64 * j)) = o;
            }
        }
        #pragma unroll
        for (int j = 0; j < 4; ++j) {
            const int f = lane + 64 * j;
            #pragma unroll
            for (int c = 0; c < 8; ++c) {
                const float4 w = *(const float4*)&WcT[c][4 * f];
                #pragma unroll
                for (int rr = 0; rr < 2; ++rr)
                    acc[2 * p + rr][c] += xv[rr][j].x * w.x + xv[rr][j].y * w.y
                                        + xv[rr][j].z * w.z + xv[rr][j].w * w.w;
            }
        }
    }

    #pragma unroll
    for (int off = 8; off < 64; off <<= 1)
        #pragma unroll
        for (int r = 0; r < 4; ++r)
            #pragma unroll
            for (int c = 0; c < 8; ++c)
                acc[r][c] += __shfl_xor(acc[r][c], off, 64);

    const int cls = lane >> 3;
    const float bcv = bc[cls];
    float s[4];
    #pragma unroll
    for (int r = 0; r < 4; ++r) {
        float v = acc[r][0];
        #pragma unroll
        for (int c = 1; c < 8; ++c) v = (cls == c) ? acc[r][c] : v;
        s[r] = v;
    }
    #pragma unroll
    for (int off = 1; off < 8; off <<= 1)
        #pragma unroll
        for (int r = 0; r < 4; ++r) s[r] += __shfl_xor(s[r], off, 64);
    #pragma unroll
    for (int r = 0; r < 4; ++r) s[r] += bcv;

    #pragma unroll
    for (int r = 0; r < 4; ++r)
        if ((lane & 7) == 0) logits_out[(size_t)(row0 + r) * CC + cls] = s[r];

    int idx[4] = {cls, cls, cls, cls};
    #pragma unroll
    for (int off = 8; off < 64; off <<= 1) {
        #pragma unroll
        for (int r = 0; r < 4; ++r) {
            const float ov = __shfl_xor(s[r], off, 64);
            const int oi = __shfl_xor(idx[r], off, 64);
            const bool take = (ov > s[r]) || (ov == s[r] && oi < idx[r]);
            s[r] = take ? ov : s[r];
            idx[r] = take ? oi : idx[r];
        }
    }
    if (lane == 0) {
        #pragma unroll
        for (int r = 0; r < 4; ++r) {
            class_idx[row0 + r] = idx[r];
            clsarr[wv * 4 + r] = idx[r];
        }
    }
    __syncthreads();
    if (tid < 64) {
        const int myc = (tid < 16) ? clsarr[tid] : -1;
        int h = 0;
        #pragma unroll
        for (int cc = 0; cc < 8; ++cc) {
            const int p = __popcll(__ballot(myc == cc));
            h = (tid == cc) ? p : h;
        }
        if (tid < 8) hist[blockIdx.x * 8 + tid] = h;
    }
}

// ---------------------------------------------------------------------------
// Single-block scan: per-class totals -> padded offsets (256-granular) +
// per-block scatter bases.
// ---------------------------------------------------------------------------
__global__ __launch_bounds__(256)
void scan_kernel(const int* __restrict__ hist, int* __restrict__ offsets,
                 int* __restrict__ bb)
{
    const int t = threadIdx.x, c = t >> 5, g = t & 31;
    int sum = 0;
    #pragma unroll 4
    for (int i = 0; i < 32; ++i) sum += hist[(g * 32 + i) * 8 + c];
    int inc = sum;
    #pragma unroll
    for (int d = 1; d < 32; d <<= 1) {
        const int v = __shfl_up(inc, d, 32);
        if (g >= d) inc += v;
    }
    __shared__ int tot[8], offL[9];
    if (g == 31) tot[c] = inc;
    __syncthreads();
    if (t == 0) {
        int o = 0; offL[0] = 0; offsets[0] = 0;
        #pragma unroll
        for (int c8 = 0; c8 < 8; ++c8) {
            o += (tot[c8] + 255) & ~255;          // pad to 256 (BM of layer GEMMs)
            offL[c8 + 1] = o; offsets[c8 + 1] = o;
        }
    }
    __syncthreads();
    int base = offL[c] + (inc - sum);
    #pragma unroll 4
    for (int i = 0; i < 32; ++i) {
        const int b = g * 32 + i;
        bb[b * 8 + c] = base;
        base += hist[b * 8 + c];
    }
}

// ---------------------------------------------------------------------------
// Scatter row ids into per-class segments — atomic-free via ballot ranking.
// ---------------------------------------------------------------------------
__global__ __launch_bounds__(256)
void scatter_kernel(const int* __restrict__ class_idx, const int* __restrict__ bb,
                    int* __restrict__ rowidx)
{
    const int r = blockIdx.x * 256 + threadIdx.x;
    const int c = class_idx[r];
    const int lane = threadIdx.x & 63;
    const int gl = lane & ~15;
    const unsigned long long before = (1ull << lane) - (1ull << gl);
    int rank = 0;
    #pragma unroll
    for (int cc = 0; cc < 8; ++cc) {
        const unsigned long long m = __ballot(c == cc);
        const int p = __popcll(m & before);
        rank = (c == cc) ? p : rank;
    }
    rowidx[bb[(r >> 4) * 8 + c] + rank] = r;
}

// ---------------------------------------------------------------------------
// R10 main GEMM (layers 1-3): B-DIRECT-TO-REGISTER design.
// Insight (R5-R9 post-mortems): kernels were LDS-read-port-bound (step time
// == b128-count x 12cy). B per class = 2 MB -> L2-resident. So: B fragments
// load global->VGPR via inline-asm global_load_dwordx4 (compiler-opaque, so
// its waitcnt pass can't inject vmcnt(0)), double-buffered bx/by across
// K-tiles. A stays glds->LDS (3 bufs, 48 KB only -> 2 blocks/CU).
// BM=256, BN=128, BK=32, 4 waves (2Mx2N), wave = 128x64 (8m x 4n frags).
// Body t: issue B(t+1) [4 asm loads] -> vmcnt(8) (keeps A(t+1),B(t+1)) ->
// s_barrier -> stage A(t+2) [4 glds, targets buf(t+2)%3=(t-1)%3 whose
// readers finished before this barrier] -> 32 MFMA with A-LDS + B-regs.
// Queue at body-t wait: B(t)4, A(t+1)4, B(t+1)4 -> vmcnt(8) drains
// A(t)/B(t) exactly. Tail: vmcnt(8) at t=30, vmcnt(0) at t=31.
// Swizzle on A (validated, conflicts=0). T1 XCD swizzle n0-inner. T5 setprio.
// ---------------------------------------------------------------------------
#define MF(a, b, c) __builtin_amdgcn_mfma_f32_16x16x32_bf16((a), (b), (c), 0, 0, 0)
// inline-asm 16B global load to VGPRs (keeps compiler's waitcnt pass out)
#define GLB(dst, p) asm volatile("global_load_dwordx4 %0, %1, off" \
                                 : "=v"(dst) : "v"(p) : "memory")

template<bool GATHER_A>
__global__ __launch_bounds__(256, 2)
void gemm_bd_kernel(const u16* __restrict__ Abase, const u16* __restrict__ Wbase,
                    size_t wclass_stride, const float* __restrict__ bias_base,
                    int bias_stride, const int* __restrict__ offsets,
                    const int* __restrict__ rowidx, u16* __restrict__ Hout)
{
    __shared__ u16 sA[3 * 8192];   // 48 KB: 3 bufs x [256 rows][32 k]
    const int tid = threadIdx.x;

    // XCD-chunked bijective swizzle (grid % 8 == 0), n0-inner
    const int bid = blockIdx.x;
    const int wg = (bid & 7) * ((int)gridDim.x >> 3) + (bid >> 3);
    const int m0 = (wg >> 3) * 256;
    const int n0 = (wg & 7) * 128;
    if (m0 >= offsets[CC]) return;
    int c = 0;
    while (m0 >= offsets[c + 1]) ++c;          // offsets are 256-multiples

    const u16* const Wcl = Wbase + (size_t)c * wclass_stride;

    // ---- A staging precompute: 4 glds/thread/tile (16 KB tile) ----
    const u16* gsrc[4];
    u16* ldst[4];
    #pragma unroll
    for (int j = 0; j < 4; ++j) {
        const int n = tid + 256 * j;            // chunk id (1024 = 256 rows x 4)
        const int row = n >> 2;
        const int logc = (n & 3) ^ ((row >> 1) & 3);   // inverse swizzle on src
        int grow = m0 + row;
        if (GATHER_A) { const int g = rowidx[grow]; grow = (g < 0) ? 0 : g; }
        gsrc[j] = Abase + (size_t)grow * 1024 + logc * 8;
        ldst[j] = sA + n * 8;                   // linear LDS dest
    }

    // ---- per-lane B global pointers (4 n-frags of 16 cols each) ----
    const int wv = tid >> 6, ln = tid & 63;
    const int wm = wv >> 1, wn = wv & 1;        // 2M x 2N wave grid
    const int lr = ln & 15, lg = ln >> 4;
    const u16* gB0 = Wcl + (size_t)(n0 + wn * 64 +  0 + lr) * 1024 + lg * 8;
    const u16* gB1 = Wcl + (size_t)(n0 + wn * 64 + 16 + lr) * 1024 + lg * 8;
    const u16* gB2 = Wcl + (size_t)(n0 + wn * 64 + 32 + lr) * 1024 + lg * 8;
    const u16* gB3 = Wcl + (size_t)(n0 + wn * 64 + 48 + lr) * 1024 + lg * 8;

    // ---- A fragment read base (swizzled; (row>>1)&3 == (lr>>1)&3) ----
    const int aoff = (wm * 128 + lr) * 32 + ((lg ^ ((lr >> 1) & 3)) * 8);

    f32x4 acc[8][4];
    #pragma unroll
    for (int i = 0; i < 8; ++i)
        #pragma unroll
        for (int j = 0; j < 4; ++j)
            acc[i][j] = (f32x4){0.f, 0.f, 0.f, 0.f};

    bf16x8 bx0, bx1, bx2, bx3, by0, by1, by2, by3;

#define STAGEA(KT, SB)                                                    \
    { GLDS16(gsrc[0] + (KT) * 32, ldst[0] + (SB) * 8192);                 \
      GLDS16(gsrc[1] + (KT) * 32, ldst[1] + (SB) * 8192);                 \
      GLDS16(gsrc[2] + (KT) * 32, ldst[2] + (SB) * 8192);                 \
      GLDS16(gsrc[3] + (KT) * 32, ldst[3] + (SB) * 8192); }

#define BLOADS(T, R0, R1, R2, R3)                                         \
    { GLB(R0, gB0 + (size_t)(T) * 32); GLB(R1, gB1 + (size_t)(T) * 32);   \
      GLB(R2, gB2 + (size_t)(T) * 32); GLB(R3, gB3 + (size_t)(T) * 32); }

#define COMPX(AB, R0, R1, R2, R3)                                         \
    { __builtin_amdgcn_s_setprio(1);                                      \
      _Pragma("unroll")                                                   \
      for (int mi = 0; mi < 8; ++mi) {                                    \
          const bf16x8 a = *(const bf16x8*)(sA + (AB) * 8192 + aoff + mi * 512); \
          acc[mi][0] = MF(a, R0, acc[mi][0]);                             \
          acc[mi][1] = MF(a, R1, acc[mi][1]);                             \
          acc[mi][2] = MF(a, R2, acc[mi][2]);                             \
          acc[mi][3] = MF(a, R3, acc[mi][3]);                             \
      }                                                                   \
      __builtin_amdgcn_s_setprio(0); }

#define BODYX(T, AB, SB, C0, C1, C2, C3, N0, N1, N2, N3, DOB, DOA, VM)    \
    {                                                                     \
        if (DOB) BLOADS((T) + 1, N0, N1, N2, N3);                         \
        asm volatile("s_waitcnt vmcnt(" #VM ")" ::: "memory");            \
        __builtin_amdgcn_s_barrier();                                     \
        __builtin_amdgcn_sched_barrier(0);                                \
        if (DOA) STAGEA((T) + 2, (SB));                                   \
        COMPX(AB, C0, C1, C2, C3);                                        \
    }

    // prologue: A(0)->buf0, B(0)->bx, A(1)->buf1  (queue: A0 B0 A1 = 12)
    STAGEA(0, 0);
    BLOADS(0, bx0, bx1, bx2, bx3);
    STAGEA(1, 1);

    for (int tb = 0; tb < 30; tb += 6) {
        BODYX(tb + 0, 0, 2, bx0, bx1, bx2, bx3, by0, by1, by2, by3, true, true, 8);
        BODYX(tb + 1, 1, 0, by0, by1, by2, by3, bx0, bx1, bx2, bx3, true, true, 8);
        BODYX(tb + 2, 2, 1, bx0, bx1, bx2, bx3, by0, by1, by2, by3, true, true, 8);
        BODYX(tb + 3, 0, 2, by0, by1, by2, by3, bx0, bx1, bx2, bx3, true, true, 8);
        BODYX(tb + 4, 1, 0, bx0, bx1, bx2, bx3, by0, by1, by2, by3, true, true, 8);
        BODYX(tb + 5, 2, 1, by0, by1, by2, by3, bx0, bx1, bx2, bx3, true, true, 8);
    }
    // t=30: loads B(31) into by; no A stage; vmcnt(8) drains B(30)
    BODYX(30, 0, 2, bx0, bx1, bx2, bx3, by0, by1, by2, by3, true, false, 8);
    // t=31: nothing to issue; drain all (A(31)+B(31) = 8 outstanding)
    BODYX(31, 1, 0, by0, by1, by2, by3, bx0, bx1, bx2, bx3, false, false, 0);

#undef BODYX
#undef COMPX
#undef BLOADS
#undef STAGEA

    // epilogue: C/D layout col=lane&15, row=(lane>>4)*4+reg; bias + ReLU
    const float* bp = bias_base + (size_t)c * bias_stride + n0 + wn * 64 + lr;
    #pragma unroll
    for (int ni = 0; ni < 4; ++ni) {
        const float bv = bp[ni * 16];
        const int col = n0 + wn * 64 + ni * 16 + lr;
        #pragma unroll
        for (int mi = 0; mi < 8; ++mi) {
            const int rb = m0 + wm * 128 + mi * 16 + lg * 4;
            #pragma unroll
            for (int q = 0; q < 4; ++q) {
                float v = acc[mi][ni][q] + bv;
                v = v > 0.f ? v : 0.f;
                Hout[(size_t)(rb + q) * HH + col] = f2bf(v);
            }
        }
    }
}

// ---------------------------------------------------------------------------
// L4 GEMM (N=256, final scatter): proven R5 structure, BM=BN=128, BK=32.
// ---------------------------------------------------------------------------
#define STAGE(b, kt)                            \
    {                                           \
        const int kb_ = (kt) * 32;              \
        GLDS16(gA0 + kb_, lA0 + (b) * 4096);    \
        GLDS16(gA1 + kb_, lA1 + (b) * 4096);    \
        GLDS16(gB0 + kb_, lB0 + (b) * 4096);    \
        GLDS16(gB1 + kb_, lB1 + (b) * 4096);    \
    }

#define COMPUTE(b)                                                        \
    {                                                                     \
        bf16x8 af[4], bfr[4];                                             \
        _Pragma("unroll")                                                 \
        for (int i = 0; i < 4; ++i) {                                     \
            af[i]  = *(const bf16x8*)(fA + (b) * 4096 + i * 16 * 32);     \
            bfr[i] = *(const bf16x8*)(fB + (b) * 4096 + i * 16 * 32);     \
        }                                                                 \
        __builtin_amdgcn_s_setprio(1);                                    \
        _Pragma("unroll")                                                 \
        for (int mi = 0; mi < 4; ++mi)                                    \
            _Pragma("unroll")                                             \
            for (int ni = 0; ni < 4; ++ni)                                \
                acc[mi][ni] = __builtin_amdgcn_mfma_f32_16x16x32_bf16(    \
                    af[mi], bfr[ni], acc[mi][ni], 0, 0, 0);               \
        __builtin_amdgcn_s_setprio(0);                                    \
    }

#define WAITV(N)                                                          \
    asm volatile("s_waitcnt vmcnt(" #N ")" ::: "memory");                 \
    __builtin_amdgcn_s_barrier();                                         \
    __builtin_amdgcn_sched_barrier(0);

__global__ __launch_bounds__(256, 3)
void gemm_final_kernel(const u16* __restrict__ Abase, const u16* __restrict__ Wbase,
                       size_t wclass_stride, const float* __restrict__ bias_base,
                       int bias_stride, const int* __restrict__ offsets,
                       const int* __restrict__ rowidx, float* __restrict__ Fout)
{
    __shared__ u16 sA[3 * 128 * 32];
    __shared__ u16 sB[3 * 128 * 32];
    const int tid = threadIdx.x;

    const int bid = blockIdx.x;
    const int wg = (bid & 7) * ((int)gridDim.x >> 3) + (bid >> 3);
    const int m0 = (wg >> 1) * 128;
    const int n0 = (wg & 1) * 128;
    if (m0 >= offsets[CC]) return;
    int c = 0;
    while (m0 >= offsets[c + 1]) ++c;

    const int srow = tid >> 2;
    const int kc8 = (tid & 3) * 8;
    const int sa0 = m0 + srow, sa1 = m0 + srow + 64;
    const u16* gA0 = Abase + (size_t)sa0 * 1024 + kc8;
    const u16* gA1 = Abase + (size_t)sa1 * 1024 + kc8;
    const u16* Wcl = Wbase + (size_t)c * wclass_stride;
    const u16* gB0 = Wcl + (size_t)(n0 + srow) * 1024 + kc8;
    const u16* gB1 = Wcl + (size_t)(n0 + srow + 64) * 1024 + kc8;
    u16* lA0 = sA + tid * 8;
    u16* lA1 = sA + 2048 + tid * 8;
    u16* lB0 = sB + tid * 8;
    u16* lB1 = sB + 2048 + tid * 8;

    const int lane = tid & 63, wv = tid >> 6;
    const int wm = (wv & 1) * 64, wn = (wv >> 1) * 64;
    const int lr = lane & 15, lg = lane >> 4;
    const u16* fA = sA + (wm + lr) * 32 + lg * 8;
    const u16* fB = sB + (wn + lr) * 32 + lg * 8;

    f32x4 acc[4][4];
    #pragma unroll
    for (int i = 0; i < 4; ++i)
        #pragma unroll
        for (int j = 0; j < 4; ++j)
            acc[i][j] = (f32x4){0.f, 0.f, 0.f, 0.f};

    STAGE(0, 0);
    STAGE(1, 1);
    for (int kt = 0; kt < 30; kt += 3) {
        WAITV(4);
        STAGE(2, kt + 2);
        COMPUTE(0);
        WAITV(4);
        STAGE(0, kt + 3);
        COMPUTE(1);
        WAITV(4);
        STAGE(1, kt + 4);
        COMPUTE(2);
    }
    WAITV(4);
    COMPUTE(0);
    WAITV(0);
    COMPUTE(1);

    const float* bp = bias_base + (size_t)c * bias_stride + n0 + wn + lr;
    #pragma unroll
    for (int ni = 0; ni < 4; ++ni) {
        const float bv = bp[ni * 16];
        const int col = n0 + wn + ni * 16 + lr;
        #pragma unroll
        for (int mi = 0; mi < 4; ++mi) {
            const int rb = m0 + wm + mi * 16 + lg * 4;
            #pragma unroll
            for (int q = 0; q < 4; ++q) {
                const float v = acc[mi][ni][q] + bv;
                const int orow = rowidx[rb + q];
                if (orow >= 0) Fout[(size_t)orow * OO + col] = v;
            }
        }
    }
}

// ---------------------------------------------------------------------------
extern "C" void kernel_launch(void* const* d_in, const int* in_sizes, int n_in,
                              void* d_out, int out_size, void* d_ws, size_t ws_size,
                              hipStream_t stream)
{
    const float* x  = (const float*)d_in[0];
    const float* Wc = (const float*)d_in[1];
    const float* bc = (const float*)d_in[2];
    const float* W1 = (const float*)d_in[3];
    const float* b1 = (const float*)d_in[4];
    const float* W2 = (const float*)d_in[5];
    const float* b2 = (const float*)d_in[6];
    const float* Wo = (const float*)d_in[7];
    const float* bo = (const float*)d_in[8];
    float* out    = (float*)d_out;                 // [B][O]
    float* logits = out + (size_t)BB * OO;         // [B][C]

    char* ws = (char*)d_ws;
    constexpr size_t PADMAX = BB + CC * 256;       // 18432 padded rows max
    constexpr int NLB = BB / 16;                   // 1024 logits blocks
    int* offsets   = (int*)(ws + 0);               // [9]
    int* hist      = (int*)(ws + 64);              // [NLB][8]
    int* bb        = (int*)(ws + 64 + NLB * 32);   // [NLB][8]
    int* class_idx = (int*)(ws + 64 + 2 * NLB * 32);
    int* rowidx    = (int*)((char*)class_idx + (size_t)BB * 4);
    u16* x_bf16    = (u16*)((char*)rowidx + PADMAX * 4);
    u16* hA  = x_bf16 + (size_t)BB * DD;
    u16* hB  = hA + PADMAX * HH;
    u16* W1T = hB + PADMAX * HH;                    // [C][H][D]
    u16* W2T = W1T + (size_t)CC * DD * HH;          // [C][2][H][H]
    u16* WoT = W2T + (size_t)CC * 2 * HH * HH;      // [C][O][H]

    hipMemsetAsync(rowidx, 0xFF, PADMAX * 4, stream);  // pad slots = -1

    transpose_bf16_kernel<<<dim3(32, 32, 8),  256, 0, stream>>>(W1, W1T, DD, HH);
    transpose_bf16_kernel<<<dim3(32, 32, 16), 256, 0, stream>>>(W2, W2T, HH, HH);
    transpose_bf16_kernel<<<dim3(8, 32, 8),   256, 0, stream>>>(Wo, WoT, HH, OO);

    logits_kernel<<<NLB, 256, 0, stream>>>(x, Wc, bc, logits, x_bf16, class_idx, hist);
    scan_kernel<<<1, 256, 0, stream>>>(hist, offsets, bb);
    scatter_kernel<<<BB / 256, 256, 0, stream>>>(class_idx, bb, rowidx);

    constexpr int MT2 = (int)(PADMAX / 256);  // 72 M-tiles (256-row)
    constexpr int MT4 = (int)(PADMAX / 128);  // 144 M-tiles (128-row, L4)
    gemm_bd_kernel<true ><<<dim3(MT2 * 8), 256, 0, stream>>>(
        x_bf16, W1T, (size_t)DD * HH, b1, HH, offsets, rowidx, hA);
    gemm_bd_kernel<false><<<dim3(MT2 * 8), 256, 0, stream>>>(
        hA, W2T, (size_t)2 * HH * HH, b2, 2 * HH, offsets, rowidx, hB);
    gemm_bd_kernel<false><<<dim3(MT2 * 8), 256, 0, stream>>>(
        hB, W2T + (size_t)HH * HH, (size_t)2 * HH * HH, b2 + HH, 2 * HH, offsets, rowidx, hA);
    gemm_final_kernel<<<dim3(MT4 * 2), 256, 0, stream>>>(
        hA, WoT, (size_t)OO * HH, bo, OO, offsets, rowidx, out);
}

// Round 11
// 320.212 us; speedup vs baseline: 1.0126x; 1.0042x over previous
//
#include <hip/hip_runtime.h>
#include <stdint.h>

// Problem constants
#define BB 16384
#define DD 1024
#define HH 1024
#define OO 256
#define CC 8

typedef unsigned short u16;
typedef __attribute__((ext_vector_type(4))) unsigned short u16x4;
typedef __attribute__((ext_vector_type(8))) short bf16x8;
typedef __attribute__((ext_vector_type(4))) float f32x4;

__device__ __forceinline__ u16 f2bf(float f) {
    union { float f; uint32_t u; } v; v.f = f;
    const uint32_t u = v.u;
    return (u16)((u + 0x7FFFu + ((u >> 16) & 1u)) >> 16);  // RNE
}

// async global->LDS, 16B per lane (dest must be wave-uniform base + lane*16)
#define GLDS16(g, l)                                                                   \
    __builtin_amdgcn_global_load_lds((const __attribute__((address_space(1))) void*)(g), \
                                     (__attribute__((address_space(3))) void*)(l), 16, 0, 0)

// ---------------------------------------------------------------------------
// Transpose fp32 [nmat][R][Cc] -> bf16 [nmat][Cc][R]  (W -> W^T, K-contiguous)
// ---------------------------------------------------------------------------
__global__ __launch_bounds__(256)
void transpose_bf16_kernel(const float* __restrict__ src, u16* __restrict__ dst,
                           int R, int Cc)
{
    __shared__ float t[32][33];
    const int tid = threadIdx.x;
    const int mat = blockIdx.z;
    const int r0 = blockIdx.y * 32, c0 = blockIdx.x * 32;
    {
        const int rr = tid >> 3, c4 = (tid & 7) * 4;
        const float4 v = *(const float4*)(src + ((size_t)mat * R + r0 + rr) * Cc + c0 + c4);
        t[rr][c4 + 0] = v.x; t[rr][c4 + 1] = v.y; t[rr][c4 + 2] = v.z; t[rr][c4 + 3] = v.w;
    }
    __syncthreads();
    {
        const int cc = tid >> 3, k4 = (tid & 7) * 4;
        u16x4 o;
        o[0] = f2bf(t[k4 + 0][cc]);
        o[1] = f2bf(t[k4 + 1][cc]);
        o[2] = f2bf(t[k4 + 2][cc]);
        o[3] = f2bf(t[k4 + 3][cc]);
        *(u16x4*)(dst + ((size_t)mat * Cc + c0 + cc) * R + r0 + k4) = o;
    }
}

// ---------------------------------------------------------------------------
// Logits (fp32, exact routing) + x -> bf16 + per-block class histogram.
// ---------------------------------------------------------------------------
__global__ __launch_bounds__(256)
void logits_kernel(const float* __restrict__ x, const float* __restrict__ Wc,
                   const float* __restrict__ bc, float* __restrict__ logits_out,
                   u16* __restrict__ x_bf16, int* __restrict__ class_idx,
                   int* __restrict__ hist)
{
    __shared__ float WcT[CC][DD];  // 32 KB, transposed classifier
    __shared__ int clsarr[16];
    const int tid = threadIdx.x;
    #pragma unroll
    for (int j = 0; j < 8; ++j) {
        const int f = tid + 256 * j;                 // float4 index into Wc [D][C]
        const float4 v = ((const float4*)Wc)[f];
        const int d = f >> 1, c = (f & 1) * 4;       // 4 elems share d (C=8)
        WcT[c + 0][d] = v.x; WcT[c + 1][d] = v.y; WcT[c + 2][d] = v.z; WcT[c + 3][d] = v.w;
    }
    __syncthreads();

    const int lane = tid & 63, wv = tid >> 6;
    const int row0 = blockIdx.x * 16 + wv * 4;

    float acc[4][8];
    #pragma unroll
    for (int r = 0; r < 4; ++r)
        #pragma unroll
        for (int c = 0; c < 8; ++c) acc[r][c] = 0.f;

    #pragma unroll
    for (int p = 0; p < 2; ++p) {
        float4 xv[2][4];
        #pragma unroll
        for (int rr = 0; rr < 2; ++rr) {
            const float4* xr = (const float4*)(x + (size_t)(row0 + 2 * p + rr) * DD);
            #pragma unroll
            for (int j = 0; j < 4; ++j) xv[rr][j] = xr[lane + 64 * j];
        }
        #pragma unroll
        for (int rr = 0; rr < 2; ++rr) {
            u16* xb = x_bf16 + (size_t)(row0 + 2 * p + rr) * DD;
            #pragma unroll
            for (int j = 0; j < 4; ++j) {
                const float4 v = xv[rr][j];
                u16x4 o; o[0] = f2bf(v.x); o[1] = f2bf(v.y); o[2] = f2bf(v.z); o[3] = f2bf(v.w);
                *(u16x4*)(xb + 4 * (lane + 64 * j)) = o;
            }
        }
        #pragma unroll
        for (int j = 0; j < 4; ++j) {
            const int f = lane + 64 * j;
            #pragma unroll
            for (int c = 0; c < 8; ++c) {
                const float4 w = *(const float4*)&WcT[c][4 * f];
                #pragma unroll
                for (int rr = 0; rr < 2; ++rr)
                    acc[2 * p + rr][c] += xv[rr][j].x * w.x + xv[rr][j].y * w.y
                                        + xv[rr][j].z * w.z + xv[rr][j].w * w.w;
            }
        }
    }

    #pragma unroll
    for (int off = 8; off < 64; off <<= 1)
        #pragma unroll
        for (int r = 0; r < 4; ++r)
            #pragma unroll
            for (int c = 0; c < 8; ++c)
                acc[r][c] += __shfl_xor(acc[r][c], off, 64);

    const int cls = lane >> 3;
    const float bcv = bc[cls];
    float s[4];
    #pragma unroll
    for (int r = 0; r < 4; ++r) {
        float v = acc[r][0];
        #pragma unroll
        for (int c = 1; c < 8; ++c) v = (cls == c) ? acc[r][c] : v;
        s[r] = v;
    }
    #pragma unroll
    for (int off = 1; off < 8; off <<= 1)
        #pragma unroll
        for (int r = 0; r < 4; ++r) s[r] += __shfl_xor(s[r], off, 64);
    #pragma unroll
    for (int r = 0; r < 4; ++r) s[r] += bcv;

    #pragma unroll
    for (int r = 0; r < 4; ++r)
        if ((lane & 7) == 0) logits_out[(size_t)(row0 + r) * CC + cls] = s[r];

    int idx[4] = {cls, cls, cls, cls};
    #pragma unroll
    for (int off = 8; off < 64; off <<= 1) {
        #pragma unroll
        for (int r = 0; r < 4; ++r) {
            const float ov = __shfl_xor(s[r], off, 64);
            const int oi = __shfl_xor(idx[r], off, 64);
            const bool take = (ov > s[r]) || (ov == s[r] && oi < idx[r]);
            s[r] = take ? ov : s[r];
            idx[r] = take ? oi : idx[r];
        }
    }
    if (lane == 0) {
        #pragma unroll
        for (int r = 0; r < 4; ++r) {
            class_idx[row0 + r] = idx[r];
            clsarr[wv * 4 + r] = idx[r];
        }
    }
    __syncthreads();
    if (tid < 64) {
        const int myc = (tid < 16) ? clsarr[tid] : -1;
        int h = 0;
        #pragma unroll
        for (int cc = 0; cc < 8; ++cc) {
            const int p = __popcll(__ballot(myc == cc));
            h = (tid == cc) ? p : h;
        }
        if (tid < 8) hist[blockIdx.x * 8 + tid] = h;
    }
}

// ---------------------------------------------------------------------------
// Single-block scan: per-class totals -> padded offsets (128-granular) +
// per-block scatter bases.
// ---------------------------------------------------------------------------
__global__ __launch_bounds__(256)
void scan_kernel(const int* __restrict__ hist, int* __restrict__ offsets,
                 int* __restrict__ bb)
{
    const int t = threadIdx.x, c = t >> 5, g = t & 31;
    int sum = 0;
    #pragma unroll 4
    for (int i = 0; i < 32; ++i) sum += hist[(g * 32 + i) * 8 + c];
    int inc = sum;
    #pragma unroll
    for (int d = 1; d < 32; d <<= 1) {
        const int v = __shfl_up(inc, d, 32);
        if (g >= d) inc += v;
    }
    __shared__ int tot[8], offL[9];
    if (g == 31) tot[c] = inc;
    __syncthreads();
    if (t == 0) {
        int o = 0; offL[0] = 0; offsets[0] = 0;
        #pragma unroll
        for (int c8 = 0; c8 < 8; ++c8) {
            o += (tot[c8] + 127) & ~127;          // pad to 128 (BM granule)
            offL[c8 + 1] = o; offsets[c8 + 1] = o;
        }
    }
    __syncthreads();
    int base = offL[c] + (inc - sum);
    #pragma unroll 4
    for (int i = 0; i < 32; ++i) {
        const int b = g * 32 + i;
        bb[b * 8 + c] = base;
        base += hist[b * 8 + c];
    }
}

// ---------------------------------------------------------------------------
// Scatter row ids into per-class segments — atomic-free via ballot ranking.
// ---------------------------------------------------------------------------
__global__ __launch_bounds__(256)
void scatter_kernel(const int* __restrict__ class_idx, const int* __restrict__ bb,
                    int* __restrict__ rowidx)
{
    const int r = blockIdx.x * 256 + threadIdx.x;
    const int c = class_idx[r];
    const int lane = threadIdx.x & 63;
    const int gl = lane & ~15;
    const unsigned long long before = (1ull << lane) - (1ull << gl);
    int rank = 0;
    #pragma unroll
    for (int cc = 0; cc < 8; ++cc) {
        const unsigned long long m = __ballot(c == cc);
        const int p = __popcll(m & before);
        rank = (c == cc) ? p : rank;
    }
    rowidx[bb[(r >> 4) * 8 + c] + rank] = r;
}

// ---------------------------------------------------------------------------
// R11 main GEMM (layers 1-3): R4's proven 2-phase dbuf structure, ONE change:
// BK=64 (barriers halved, 16 per block instead of 32). Session evidence:
// perf tracks residency (R3/R4 2-resident best); schedule heroics at 1-2
// resident all regressed. This keeps 2-resident (64 KB LDS dbuf) and
// amortizes the per-barrier vmcnt drain over 2x compute (32 MFMA, 16 b128).
// 128-B rows would be a 16-way bank conflict -> R8-validated chunk^(row&7)
// swizzle both sides (measured 0 conflicts in this exact layout).
// BM=BN=128, 256 thr / 4 waves (2Mx2N), wave = 64x64. T1 XCD swizzle.
// ---------------------------------------------------------------------------
#define MF(a, b, c) __builtin_amdgcn_mfma_f32_16x16x32_bf16((a), (b), (c), 0, 0, 0)

template<bool GATHER_A>
__global__ __launch_bounds__(256)
void gemm_kernel(const u16* __restrict__ Abase, const u16* __restrict__ Wbase,
                 size_t wclass_stride, const float* __restrict__ bias_base,
                 int bias_stride, const int* __restrict__ offsets,
                 const int* __restrict__ rowidx, u16* __restrict__ Hout)
{
    __shared__ u16 sA[2 * 8192];   // 32 KB: 2 bufs x [128 rows][64 k]
    __shared__ u16 sB[2 * 8192];   // 32 KB
    const int tid = threadIdx.x;

    // XCD-chunked bijective swizzle (grid % 8 == 0), n0-inner
    const int bid = blockIdx.x;
    const int wg = (bid & 7) * ((int)gridDim.x >> 3) + (bid >> 3);
    const int m0 = (wg >> 3) * 128;
    const int n0 = (wg & 7) * 128;
    if (m0 >= offsets[CC]) return;
    int c = 0;
    while (m0 >= offsets[c + 1]) ++c;          // offsets are 128-multiples

    const u16* const Wcl = Wbase + (size_t)c * wclass_stride;

    // ---- staging precompute: 4 A-chunks + 4 B-chunks per thread per K-tile.
    // chunk n = tid + 256*j in [0,1024): row = n>>3, chunk-in-row = n&7.
    // swizzle: LDS dest linear at n*8; global source column (n&7)^(row&7).
    const u16* gsA[4]; const u16* gsB[4];
    int dn[4];
    #pragma unroll
    for (int j = 0; j < 4; ++j) {
        const int n = tid + 256 * j;
        const int row = n >> 3;
        const int logc = (n & 7) ^ (row & 7);   // inverse swizzle on source
        int grow = m0 + row;
        if (GATHER_A) { const int g = rowidx[grow]; grow = (g < 0) ? 0 : g; }
        gsA[j] = Abase + (size_t)grow * 1024 + logc * 8;
        gsB[j] = Wcl + (size_t)(n0 + row) * 1024 + logc * 8;
        dn[j] = n * 8;
    }

#define STAGE(SB, KT)                                                     \
    { GLDS16(gsA[0] + (KT) * 64, sA + (SB) * 8192 + dn[0]);               \
      GLDS16(gsA[1] + (KT) * 64, sA + (SB) * 8192 + dn[1]);               \
      GLDS16(gsA[2] + (KT) * 64, sA + (SB) * 8192 + dn[2]);               \
      GLDS16(gsA[3] + (KT) * 64, sA + (SB) * 8192 + dn[3]);               \
      GLDS16(gsB[0] + (KT) * 64, sB + (SB) * 8192 + dn[0]);               \
      GLDS16(gsB[1] + (KT) * 64, sB + (SB) * 8192 + dn[1]);               \
      GLDS16(gsB[2] + (KT) * 64, sB + (SB) * 8192 + dn[2]);               \
      GLDS16(gsB[3] + (KT) * 64, sB + (SB) * 8192 + dn[3]); }

    // ---- fragment read bases (swizzled): row = base+mi*16+lr, row&7 = lr&7.
    // phys chunk for (kh, lg) = (kh*4+lg) ^ (lr&7).
    const int wv = tid >> 6, ln = tid & 63;
    const int wm = (wv & 1) * 64, wn = (wv >> 1) * 64;
    const int lr = ln & 15, lg = ln >> 4;
    const int s7 = lr & 7;
    const int pc0 = ((0 * 4 + lg) ^ s7) * 8;     // kh=0 chunk byte-offset/2
    const int pc1 = ((1 * 4 + lg) ^ s7) * 8;     // kh=1
    const u16* const fA = sA + (wm + lr) * 64;   // + mi*1024 + pc{0,1} + buf*8192
    const u16* const fB = sB + (wn + lr) * 64;

    f32x4 acc[4][4];
    #pragma unroll
    for (int i = 0; i < 4; ++i)
        #pragma unroll
        for (int j = 0; j < 4; ++j)
            acc[i][j] = (f32x4){0.f, 0.f, 0.f, 0.f};

#define COMPUTE(SB)                                                       \
    {                                                                     \
        bf16x8 a0[4], b0[4], a1[4], b1[4];                                \
        _Pragma("unroll")                                                 \
        for (int i = 0; i < 4; ++i) {                                     \
            a0[i] = *(const bf16x8*)(fA + (SB) * 8192 + i * 1024 + pc0);  \
            b0[i] = *(const bf16x8*)(fB + (SB) * 8192 + i * 1024 + pc0);  \
        }                                                                 \
        __builtin_amdgcn_s_setprio(1);                                    \
        _Pragma("unroll")                                                 \
        for (int mi = 0; mi < 4; ++mi)                                    \
            _Pragma("unroll")                                             \
            for (int ni = 0; ni < 4; ++ni)                                \
                acc[mi][ni] = MF(a0[mi], b0[ni], acc[mi][ni]);            \
        __builtin_amdgcn_s_setprio(0);                                    \
        _Pragma("unroll")                                                 \
        for (int i = 0; i < 4; ++i) {                                     \
            a1[i] = *(const bf16x8*)(fA + (SB) * 8192 + i * 1024 + pc1);  \
            b1[i] = *(const bf16x8*)(fB + (SB) * 8192 + i * 1024 + pc1);  \
        }                                                                 \
        __builtin_amdgcn_s_setprio(1);                                    \
        _Pragma("unroll")                                                 \
        for (int mi = 0; mi < 4; ++mi)                                    \
            _Pragma("unroll")                                             \
            for (int ni = 0; ni < 4; ++ni)                                \
                acc[mi][ni] = MF(a1[mi], b1[ni], acc[mi][ni]);            \
        __builtin_amdgcn_s_setprio(0);                                    \
    }

    // prologue: tile 0 -> buf 0
    STAGE(0, 0);
    __syncthreads();
    // 16 K-tiles; stage t+1 into other buf, compute t, sync (R4 schedule)
    for (int t = 0; t < 14; t += 2) {
        STAGE(1, t + 1); COMPUTE(0); __syncthreads();
        STAGE(0, t + 2); COMPUTE(1); __syncthreads();
    }
    STAGE(1, 15); COMPUTE(0); __syncthreads();
    COMPUTE(1);

#undef COMPUTE
#undef STAGE

    // epilogue: C/D layout col=lane&15, row=(lane>>4)*4+reg; bias + ReLU
    const float* bp = bias_base + (size_t)c * bias_stride + n0 + wn + lr;
    #pragma unroll
    for (int ni = 0; ni < 4; ++ni) {
        const float bv = bp[ni * 16];
        const int col = n0 + wn + ni * 16 + lr;
        #pragma unroll
        for (int mi = 0; mi < 4; ++mi) {
            const int rb = m0 + wm + mi * 16 + lg * 4;
            #pragma unroll
            for (int q = 0; q < 4; ++q) {
                float v = acc[mi][ni][q] + bv;
                v = v > 0.f ? v : 0.f;
                Hout[(size_t)(rb + q) * HH + col] = f2bf(v);
            }
        }
    }
}

// ---------------------------------------------------------------------------
// L4 GEMM (N=256, final scatter): proven R5 structure, BM=BN=128, BK=32.
// ---------------------------------------------------------------------------
#define STAGE4(b, kt)                           \
    {                                           \
        const int kb_ = (kt) * 32;              \
        GLDS16(gA0 + kb_, lA0 + (b) * 4096);    \
        GLDS16(gA1 + kb_, lA1 + (b) * 4096);    \
        GLDS16(gB0 + kb_, lB0 + (b) * 4096);    \
        GLDS16(gB1 + kb_, lB1 + (b) * 4096);    \
    }

#define COMPUTE4(b)                                                       \
    {                                                                     \
        bf16x8 af[4], bfr[4];                                             \
        _Pragma("unroll")                                                 \
        for (int i = 0; i < 4; ++i) {                                     \
            af[i]  = *(const bf16x8*)(fA + (b) * 4096 + i * 16 * 32);     \
            bfr[i] = *(const bf16x8*)(fB + (b) * 4096 + i * 16 * 32);     \
        }                                                                 \
        __builtin_amdgcn_s_setprio(1);                                    \
        _Pragma("unroll")                                                 \
        for (int mi = 0; mi < 4; ++mi)                                    \
            _Pragma("unroll")                                             \
            for (int ni = 0; ni < 4; ++ni)                                \
                acc[mi][ni] = __builtin_amdgcn_mfma_f32_16x16x32_bf16(    \
                    af[mi], bfr[ni], acc[mi][ni], 0, 0, 0);               \
        __builtin_amdgcn_s_setprio(0);                                    \
    }

#define WAITV(N)                                                          \
    asm volatile("s_waitcnt vmcnt(" #N ")" ::: "memory");                 \
    __builtin_amdgcn_s_barrier();                                         \
    __builtin_amdgcn_sched_barrier(0);

__global__ __launch_bounds__(256, 3)
void gemm_final_kernel(const u16* __restrict__ Abase, const u16* __restrict__ Wbase,
                       size_t wclass_stride, const float* __restrict__ bias_base,
                       int bias_stride, const int* __restrict__ offsets,
                       const int* __restrict__ rowidx, float* __restrict__ Fout)
{
    __shared__ u16 sA[3 * 128 * 32];
    __shared__ u16 sB[3 * 128 * 32];
    const int tid = threadIdx.x;

    const int bid = blockIdx.x;
    const int wg = (bid & 7) * ((int)gridDim.x >> 3) + (bid >> 3);
    const int m0 = (wg >> 1) * 128;
    const int n0 = (wg & 1) * 128;
    if (m0 >= offsets[CC]) return;
    int c = 0;
    while (m0 >= offsets[c + 1]) ++c;

    const int srow = tid >> 2;
    const int kc8 = (tid & 3) * 8;
    const int sa0 = m0 + srow, sa1 = m0 + srow + 64;
    const u16* gA0 = Abase + (size_t)sa0 * 1024 + kc8;
    const u16* gA1 = Abase + (size_t)sa1 * 1024 + kc8;
    const u16* Wcl = Wbase + (size_t)c * wclass_stride;
    const u16* gB0 = Wcl + (size_t)(n0 + srow) * 1024 + kc8;
    const u16* gB1 = Wcl + (size_t)(n0 + srow + 64) * 1024 + kc8;
    u16* lA0 = sA + tid * 8;
    u16* lA1 = sA + 2048 + tid * 8;
    u16* lB0 = sB + tid * 8;
    u16* lB1 = sB + 2048 + tid * 8;

    const int lane = tid & 63, wv = tid >> 6;
    const int wm = (wv & 1) * 64, wn = (wv >> 1) * 64;
    const int lr = lane & 15, lg = lane >> 4;
    const u16* fA = sA + (wm + lr) * 32 + lg * 8;
    const u16* fB = sB + (wn + lr) * 32 + lg * 8;

    f32x4 acc[4][4];
    #pragma unroll
    for (int i = 0; i < 4; ++i)
        #pragma unroll
        for (int j = 0; j < 4; ++j)
            acc[i][j] = (f32x4){0.f, 0.f, 0.f, 0.f};

    STAGE4(0, 0);
    STAGE4(1, 1);
    for (int kt = 0; kt < 30; kt += 3) {
        WAITV(4);
        STAGE4(2, kt + 2);
        COMPUTE4(0);
        WAITV(4);
        STAGE4(0, kt + 3);
        COMPUTE4(1);
        WAITV(4);
        STAGE4(1, kt + 4);
        COMPUTE4(2);
    }
    WAITV(4);
    COMPUTE4(0);
    WAITV(0);
    COMPUTE4(1);

    const float* bp = bias_base + (size_t)c * bias_stride + n0 + wn + lr;
    #pragma unroll
    for (int ni = 0; ni < 4; ++ni) {
        const float bv = bp[ni * 16];
        const int col = n0 + wn + ni * 16 + lr;
        #pragma unroll
        for (int mi = 0; mi < 4; ++mi) {
            const int rb = m0 + wm + mi * 16 + lg * 4;
            #pragma unroll
            for (int q = 0; q < 4; ++q) {
                const float v = acc[mi][ni][q] + bv;
                const int orow = rowidx[rb + q];
                if (orow >= 0) Fout[(size_t)orow * OO + col] = v;
            }
        }
    }
}

// ---------------------------------------------------------------------------
extern "C" void kernel_launch(void* const* d_in, const int* in_sizes, int n_in,
                              void* d_out, int out_size, void* d_ws, size_t ws_size,
                              hipStream_t stream)
{
    const float* x  = (const float*)d_in[0];
    const float* Wc = (const float*)d_in[1];
    const float* bc = (const float*)d_in[2];
    const float* W1 = (const float*)d_in[3];
    const float* b1 = (const float*)d_in[4];
    const float* W2 = (const float*)d_in[5];
    const float* b2 = (const float*)d_in[6];
    const float* Wo = (const float*)d_in[7];
    const float* bo = (const float*)d_in[8];
    float* out    = (float*)d_out;                 // [B][O]
    float* logits = out + (size_t)BB * OO;         // [B][C]

    char* ws = (char*)d_ws;
    constexpr size_t PADMAX = BB + CC * 128;       // 17408 padded rows max
    constexpr int NLB = BB / 16;                   // 1024 logits blocks
    int* offsets   = (int*)(ws + 0);               // [9]
    int* hist      = (int*)(ws + 64);              // [NLB][8]
    int* bb        = (int*)(ws + 64 + NLB * 32);   // [NLB][8]
    int* class_idx = (int*)(ws + 64 + 2 * NLB * 32);
    int* rowidx    = (int*)((char*)class_idx + (size_t)BB * 4);
    u16* x_bf16    = (u16*)((char*)rowidx + PADMAX * 4);
    u16* hA  = x_bf16 + (size_t)BB * DD;
    u16* hB  = hA + PADMAX * HH;
    u16* W1T = hB + PADMAX * HH;                    // [C][H][D]
    u16* W2T = W1T + (size_t)CC * DD * HH;          // [C][2][H][H]
    u16* WoT = W2T + (size_t)CC * 2 * HH * HH;      // [C][O][H]

    hipMemsetAsync(rowidx, 0xFF, PADMAX * 4, stream);  // pad slots = -1

    transpose_bf16_kernel<<<dim3(32, 32, 8),  256, 0, stream>>>(W1, W1T, DD, HH);
    transpose_bf16_kernel<<<dim3(32, 32, 16), 256, 0, stream>>>(W2, W2T, HH, HH);
    transpose_bf16_kernel<<<dim3(8, 32, 8),   256, 0, stream>>>(Wo, WoT, HH, OO);

    logits_kernel<<<NLB, 256, 0, stream>>>(x, Wc, bc, logits, x_bf16, class_idx, hist);
    scan_kernel<<<1, 256, 0, stream>>>(hist, offsets, bb);
    scatter_kernel<<<BB / 256, 256, 0, stream>>>(class_idx, bb, rowidx);

    constexpr int MT = (int)(PADMAX / 128);   // 136 M-tiles
    gemm_kernel<true ><<<dim3(MT * 8), 256, 0, stream>>>(
        x_bf16, W1T, (size_t)DD * HH, b1, HH, offsets, rowidx, hA);
    gemm_kernel<false><<<dim3(MT * 8), 256, 0, stream>>>(
        hA, W2T, (size_t)2 * HH * HH, b2, 2 * HH, offsets, rowidx, hB);
    gemm_kernel<false><<<dim3(MT * 8), 256, 0, stream>>>(
        hB, W2T + (size_t)HH * HH, (size_t)2 * HH * HH, b2 + HH, 2 * HH, offsets, rowidx, hA);
    gemm_final_kernel<<<dim3(MT * 2), 256, 0, stream>>>(
        hA, WoT, (size_t)OO * HH, bo, OO, offsets, rowidx, out);
}